// Round 4
// baseline (172.787 us; speedup 1.0000x reference)
//
#include <hip/hip_runtime.h>
#include <math.h>

#define BB 32
#define HH 256
#define WW 256
#define HW (HH*WW)
#define TOT (BB*HW)
#define K_BG 0.1f
#define RELAX 5.0f
#define EPS_D 1e-7
#define NBF 2048         // k_final blocks (grid-stride x4)

typedef unsigned long long u64;
typedef unsigned short u16;

__device__ __forceinline__ float sigf(float x) { return 1.0f / (1.0f + expf(-x)); }

// ---------------- binary 5x5 dilation as bit-ops -> nonzero mask ----------------
// targets are {0,1}; dilated-nonzero mask, 4 u64 words per row.
__global__ void k_maskdil(const float* __restrict__ tg, u64* __restrict__ dmask) {
    __shared__ u64 nz[36][4];
    __shared__ u64 hd[36][4];
    int blk = blockIdx.x;              // 32 images x 8 bands of 32 rows
    int b = blk >> 3, band = blk & 7;
    int r0 = band * 32;
    int t = threadIdx.x, w = t >> 6;
    const float* img = tg + b * HW;
    for (int rr = 0; rr < 36; ++rr) {
        int rg = r0 + rr - 2;
        float v = (rg >= 0 && rg < HH) ? img[rg * WW + t] : 0.0f;
        u64 bal = __ballot(v != 0.0f);
        if ((t & 63) == 0) nz[rr][w] = bal;
    }
    __syncthreads();
    if (t < 144) {                     // 36 rows x 4 words: horizontal +-2 dilate
        int rr = t >> 2, k = t & 3;
        u64 m = nz[rr][k];
        u64 ml = (k > 0) ? nz[rr][k - 1] : 0ULL;
        u64 mr = (k < 3) ? nz[rr][k + 1] : 0ULL;
        hd[rr][k] = m | (m << 1) | (m << 2) | (m >> 1) | (m >> 2)
                  | (ml >> 62) | (ml >> 63) | (mr << 62) | (mr << 63);
    }
    __syncthreads();
    if (t < 128) {                     // 32 rows x 4 words: vertical +-2 dilate
        int rr = t >> 2, k = t & 3;
        u64 o = hd[rr][k] | hd[rr + 1][k] | hd[rr + 2][k] | hd[rr + 3][k] | hd[rr + 4][k];
        dmask[b * 1024 + (r0 + rr) * 4 + k] = o;
    }
}

// ---------------- exact separable EDT, fully LDS-resident per image ----------------
// vertical fwd/bwd 1D distance (clamped 1e4) then per-row min-plus with early exit.
// Matches reference f32 arithmetic exactly (1e8 and v*v+r*r exact in f32).
__global__ __launch_bounds__(512) void k_edt(const u64* __restrict__ dmask,
                                             float* __restrict__ d,
                                             float* __restrict__ dmnb,
                                             float* __restrict__ dmxb) {
    __shared__ u64 mk[1024];           // 8 KB: nonzero mask, [row][word]
    __shared__ u16 gS[HH][WW];         // 128 KB: vertical distances
    __shared__ float smn[8], smx[8];
    int b = blockIdx.x, tid = threadIdx.x;
    const u64* src = dmask + b * 1024;
    for (int w = tid; w < 1024; w += 512) mk[w] = src[w];
    __syncthreads();
    if (tid < WW) {                    // thread = column; fwd then bwd scan
        int j = tid, wsel = j >> 6, bsel = j & 63;
        int carry = 10000;
        for (int i = 0; i < HH; ++i) {
            int nzb = (int)((mk[i * 4 + wsel] >> bsel) & 1ULL);
            carry = nzb ? min(carry + 1, 10000) : 0;
            gS[i][j] = (u16)carry;
        }
        carry = 10000;
        for (int i = HH - 1; i >= 0; --i) {
            int nzb = (int)((mk[i * 4 + wsel] >> bsel) & 1ULL);
            carry = nzb ? min(carry + 1, 10000) : 0;
            int cur = gS[i][j];
            gS[i][j] = (u16)min(cur, carry);
        }
    }
    __syncthreads();
    int j = tid & 255, half = tid >> 8;    // 512 threads: 2 row-halves
    float mn = 1e30f, mx = 0.0f;
    float* drow = d + (long)b * HW;
    for (int i = half * 128; i < half * 128 + 128; ++i) {
        float g0 = (float)gS[i][j];
        float best = g0 * g0;
        for (int r = 1; r < WW; ++r) {
            float rr = (float)(r * r);
            if (rr >= best) break;
            int jl = j - r, jr = j + r;
            if (jl >= 0)  { float v = (float)gS[i][jl]; best = fminf(best, v * v + rr); }
            if (jr < WW)  { float v = (float)gS[i][jr]; best = fminf(best, v * v + rr); }
        }
        float dv = sqrtf(best);
        drow[i * WW + j] = dv;
        mn = fminf(mn, dv); mx = fmaxf(mx, dv);
    }
    for (int off = 32; off > 0; off >>= 1) {
        mn = fminf(mn, __shfl_down(mn, off, 64));
        mx = fmaxf(mx, __shfl_down(mx, off, 64));
    }
    int wid = tid >> 6, lane = tid & 63;
    if (lane == 0) { smn[wid] = mn; smx[wid] = mx; }
    __syncthreads();
    if (tid == 0) {
        float a = smn[0], z = smx[0];
        for (int k = 1; k < 8; ++k) { a = fminf(a, smn[k]); z = fmaxf(z, smx[k]); }
        dmnb[b] = a; dmxb[b] = z;
    }
}

// ---------------- fused distance-map + dice partial sums (no atomics) ----------------
__global__ void k_final(const float* __restrict__ preds, const float* __restrict__ tg,
                        const u64* __restrict__ dmask, const float* __restrict__ d,
                        const float* __restrict__ dmnb, const float* __restrict__ dmxb,
                        float2* __restrict__ part) {
    int tid = blockIdx.x * blockDim.x + threadIdx.x;
    const int stride = NBF * 256;
    float inter = 0.0f, card = 0.0f;
    #pragma unroll
    for (int it = 0; it < TOT / stride; ++it) {
        int idx = tid + it * stride;
        int b = idx / HW;
        float t = tg[idx];
        float dmx = dmxb[b];
        float dm;
        if (dmx > 0.0f) {                       // has foreground
            float smin = sigf(dmnb[b] / RELAX);
            float smax = sigf(dmx / RELAX);
            float mxs = smax - smin;
            float denom = (mxs > 0.0f) ? mxs : 1.0f;
            float soft = (sigf(d[idx] / RELAX) - smin) / denom;
            float fat = (float)((dmask[idx >> 6] >> (idx & 63)) & 1ULL);
            dm = soft + (1.0f - fat) * K_BG;
        } else {
            dm = 1.0f - t;
        }
        float pw = sigf(preds[idx]) * dm;
        inter += pw * t;
        card += pw + t;
    }
    for (int off = 32; off > 0; off >>= 1) {
        inter += __shfl_down(inter, off, 64);
        card  += __shfl_down(card,  off, 64);
    }
    __shared__ float si[4], sc[4];
    int wid = threadIdx.x >> 6, lane = threadIdx.x & 63;
    if (lane == 0) { si[wid] = inter; sc[wid] = card; }
    __syncthreads();
    if (threadIdx.x == 0) {
        float ti = 0.0f, tc = 0.0f;
        for (int i = 0; i < 4; ++i) { ti += si[i]; tc += sc[i]; }
        part[blockIdx.x] = make_float2(ti, tc);
    }
}

// ---------------- finalize scalar: reduce partials in double ----------------
__global__ void k_fin(const float2* __restrict__ part, const float* __restrict__ dmxb,
                      float* __restrict__ out) {
    int t = threadIdx.x;
    double di = 0.0, dc = 0.0;
    for (int i = t; i < NBF; i += 256) { di += (double)part[i].x; dc += (double)part[i].y; }
    for (int off = 32; off > 0; off >>= 1) {
        di += __shfl_down(di, off, 64);
        dc += __shfl_down(dc, off, 64);
    }
    __shared__ double sdi[4], sdc[4];
    int wid = t >> 6, lane = t & 63;
    if (lane == 0) { sdi[wid] = di; sdc[wid] = dc; }
    __syncthreads();
    if (t == 0) {
        double I = 0.0, C = 0.0;
        for (int i = 0; i < 4; ++i) { I += sdi[i]; C += sdc[i]; }
        int any = 0;
        for (int b = 0; b < BB; ++b) any |= (dmxb[b] > 0.0f);
        double dice = 2.0 * I / fmax(C, (double)EPS_D);
        out[0] = any ? (float)(1.0 - dice) : 0.0f;
    }
}

extern "C" void kernel_launch(void* const* d_in, const int* in_sizes, int n_in,
                              void* d_out, int out_size, void* d_ws, size_t ws_size,
                              hipStream_t stream) {
    const float* preds = (const float*)d_in[0];
    const float* tg    = (const float*)d_in[1];
    float* out = (float*)d_out;

    float* darr = (float*)d_ws;                  // 8 MB
    u64* dmask  = (u64*)(darr + TOT);            // 256 KB, 8B-aligned (8MB offset)
    float2* part = (float2*)(dmask + BB * 1024); // 16 KB
    float* dmnb = (float*)(part + NBF);
    float* dmxb = dmnb + BB;

    hipLaunchKernelGGL(k_maskdil, dim3(BB * 8), dim3(WW), 0, stream, tg, dmask);
    hipLaunchKernelGGL(k_edt, dim3(BB), dim3(512), 0, stream, dmask, darr, dmnb, dmxb);
    hipLaunchKernelGGL(k_final, dim3(NBF), dim3(256), 0, stream, preds, tg, dmask, darr,
                       dmnb, dmxb, part);
    hipLaunchKernelGGL(k_fin, dim3(1), dim3(256), 0, stream, part, dmxb, out);
}

// Round 5
// 104.655 us; speedup vs baseline: 1.6510x; 1.6510x over previous
//
#include <hip/hip_runtime.h>
#include <math.h>

#define BB 32
#define HH 256
#define WW 256
#define HW (HH*WW)
#define TOT (BB*HW)
#define K_BG 0.1f
#define RELAX 5.0f
#define EPS_D 1e-7
#define NBF 2048         // k_final blocks (1 float4 per thread)

typedef unsigned long long u64;
typedef unsigned short u16;

__device__ __forceinline__ float sigf(float x) { return 1.0f / (1.0f + expf(-x)); }

// ---------------- binary 5x5 dilation as bit-ops -> dilated row masks ----------------
// dmask[b*1024 + i*4 + w]: bit j of word w = (dilated target)[b][i][64w+j] != 0
__global__ void k_maskdil(const float* __restrict__ tg, u64* __restrict__ dmask) {
    __shared__ u64 nz[12][4];
    __shared__ u64 hd[12][4];
    int blk = blockIdx.x;              // 32 images x 32 bands of 8 rows
    int b = blk >> 5, band = blk & 31;
    int r0 = band * 8;
    int t = threadIdx.x, w = t >> 6;
    const float* img = tg + b * HW;
    for (int rr = 0; rr < 12; ++rr) {
        int rg = r0 + rr - 2;
        float v = (rg >= 0 && rg < HH) ? img[rg * WW + t] : 0.0f;
        u64 bal = __ballot(v != 0.0f);
        if ((t & 63) == 0) nz[rr][w] = bal;
    }
    __syncthreads();
    if (t < 48) {                      // 12 rows x 4 words: horizontal +-2 dilate
        int rr = t >> 2, k = t & 3;
        u64 m = nz[rr][k];
        u64 ml = (k > 0) ? nz[rr][k - 1] : 0ULL;
        u64 mr = (k < 3) ? nz[rr][k + 1] : 0ULL;
        hd[rr][k] = m | (m << 1) | (m << 2) | (m >> 1) | (m >> 2)
                  | (ml >> 62) | (ml >> 63) | (mr << 62) | (mr << 63);
    }
    __syncthreads();
    if (t < 32) {                      // 8 rows x 4 words: vertical +-2 dilate
        int rr = t >> 2, k = t & 3;
        u64 o = hd[rr][k] | hd[rr + 1][k] | hd[rr + 2][k] | hd[rr + 3][k] | hd[rr + 4][k];
        dmask[b * 1024 + (r0 + rr) * 4 + k] = o;
    }
}

// ---------------- exact separable EDT, one block per row ----------------
// vertical distance via bit-scan in the LDS-resident image mask (broadcast reads),
// then per-row min-plus walk with early exit. Matches reference f32 arithmetic.
__global__ __launch_bounds__(256) void k_edt(const u64* __restrict__ dmask,
                                             float* __restrict__ d,
                                             float* __restrict__ rowmn,
                                             float* __restrict__ rowmx) {
    __shared__ u64 mk[1024];           // 8 KB: image's dilated row masks
    __shared__ u16 gS[WW];
    __shared__ float smn[4], smx[4];
    int row = blockIdx.x;              // b*256 + i
    int b = row >> 8, i = row & 255;
    int t = threadIdx.x;
    const uint4* src4 = (const uint4*)(dmask + b * 1024);
    uint4* mk4 = (uint4*)mk;
    mk4[t] = src4[t];
    mk4[t + 256] = src4[t + 256];
    __syncthreads();

    int j = t, w = j >> 6;
    u64 bitm = 1ULL << (j & 63);
    int g0 = 0;
    if (mk[i * 4 + w] & bitm) {
        int up = 10000;
        for (int k = 1; k <= i; ++k)
            if (!(mk[(i - k) * 4 + w] & bitm)) { up = k; break; }
        int dn = 10000;
        for (int k = 1; k < HH - i; ++k)
            if (!(mk[(i + k) * 4 + w] & bitm)) { dn = k; break; }
        g0 = min(up, dn);
    }
    gS[j] = (u16)g0;
    __syncthreads();

    float gv = (float)g0;
    float best = gv * gv;
    for (int r = 1; r < WW; ++r) {
        float rr = (float)(r * r);
        if (rr >= best) break;
        int jl = j - r, jr = j + r;
        if (jl >= 0) { float v = (float)gS[jl]; best = fminf(best, v * v + rr); }
        if (jr < WW) { float v = (float)gS[jr]; best = fminf(best, v * v + rr); }
    }
    float dv = sqrtf(best);
    d[(long)row * WW + j] = dv;

    float mn = dv, mx = dv;
    for (int off = 32; off > 0; off >>= 1) {
        mn = fminf(mn, __shfl_down(mn, off, 64));
        mx = fmaxf(mx, __shfl_down(mx, off, 64));
    }
    int wid = t >> 6, lane = t & 63;
    if (lane == 0) { smn[wid] = mn; smx[wid] = mx; }
    __syncthreads();
    if (t == 0) {
        float a = smn[0], z = smx[0];
        for (int k = 1; k < 4; ++k) { a = fminf(a, smn[k]); z = fmaxf(z, smx[k]); }
        rowmn[row] = a; rowmx[row] = z;
    }
}

// ---------------- per-batch min/max of d (no atomics) ----------------
__global__ void k_mnmx(const float* __restrict__ rowmn, const float* __restrict__ rowmx,
                       float* __restrict__ dmnb, float* __restrict__ dmxb) {
    int b = blockIdx.x, t = threadIdx.x;
    float mn = rowmn[b * HH + t], mx = rowmx[b * HH + t];
    for (int off = 32; off > 0; off >>= 1) {
        mn = fminf(mn, __shfl_down(mn, off, 64));
        mx = fmaxf(mx, __shfl_down(mx, off, 64));
    }
    __shared__ float smn[4], smx[4];
    int wid = t >> 6, lane = t & 63;
    if (lane == 0) { smn[wid] = mn; smx[wid] = mx; }
    __syncthreads();
    if (t == 0) {
        float a = smn[0], z = smx[0];
        for (int k = 1; k < 4; ++k) { a = fminf(a, smn[k]); z = fmaxf(z, smx[k]); }
        dmnb[b] = a; dmxb[b] = z;
    }
}

// ---------------- fused distance-map + dice partial sums (float4, no atomics) ----------------
__global__ void k_final(const float4* __restrict__ preds4, const float4* __restrict__ tg4,
                        const u64* __restrict__ dmask, const float4* __restrict__ d4,
                        const float* __restrict__ dmnb, const float* __restrict__ dmxb,
                        float2* __restrict__ part) {
    int tid = blockIdx.x * blockDim.x + threadIdx.x;  // one float4 per thread
    int idx = tid << 2;
    int b = idx / HW;
    float4 p = preds4[tid], tv = tg4[tid], dd = d4[tid];
    u64 mword = dmask[idx >> 6];
    int sh = idx & 63;
    float pe[4] = {p.x, p.y, p.z, p.w};
    float te[4] = {tv.x, tv.y, tv.z, tv.w};
    float de[4] = {dd.x, dd.y, dd.z, dd.w};
    float dmx = dmxb[b];
    float inter = 0.0f, card = 0.0f;
    if (dmx > 0.0f) {                  // has foreground
        float smin = sigf(dmnb[b] / RELAX);
        float smax = sigf(dmx / RELAX);
        float m = smax - smin;
        float denom = (m > 0.0f) ? m : 1.0f;
        #pragma unroll
        for (int e = 0; e < 4; ++e) {
            float fat = (float)((mword >> (sh + e)) & 1ULL);
            float soft = (sigf(de[e] / RELAX) - smin) / denom;
            float dm = soft + (1.0f - fat) * K_BG;
            float pw = sigf(pe[e]) * dm;
            inter += pw * te[e];
            card += pw + te[e];
        }
    } else {
        #pragma unroll
        for (int e = 0; e < 4; ++e) {
            float dm = 1.0f - te[e];
            float pw = sigf(pe[e]) * dm;
            inter += pw * te[e];
            card += pw + te[e];
        }
    }
    for (int off = 32; off > 0; off >>= 1) {
        inter += __shfl_down(inter, off, 64);
        card  += __shfl_down(card,  off, 64);
    }
    __shared__ float si[4], sc[4];
    int wid = threadIdx.x >> 6, lane = threadIdx.x & 63;
    if (lane == 0) { si[wid] = inter; sc[wid] = card; }
    __syncthreads();
    if (threadIdx.x == 0) {
        float ti = 0.0f, tc = 0.0f;
        for (int i = 0; i < 4; ++i) { ti += si[i]; tc += sc[i]; }
        part[blockIdx.x] = make_float2(ti, tc);
    }
}

// ---------------- finalize scalar: reduce partials in double ----------------
__global__ void k_fin(const float2* __restrict__ part, const float* __restrict__ dmxb,
                      float* __restrict__ out) {
    int t = threadIdx.x;
    double di = 0.0, dc = 0.0;
    for (int i = t; i < NBF; i += 256) { di += (double)part[i].x; dc += (double)part[i].y; }
    for (int off = 32; off > 0; off >>= 1) {
        di += __shfl_down(di, off, 64);
        dc += __shfl_down(dc, off, 64);
    }
    __shared__ double sdi[4], sdc[4];
    int wid = t >> 6, lane = t & 63;
    if (lane == 0) { sdi[wid] = di; sdc[wid] = dc; }
    __syncthreads();
    if (t == 0) {
        double I = 0.0, C = 0.0;
        for (int i = 0; i < 4; ++i) { I += sdi[i]; C += sdc[i]; }
        int any = 0;
        for (int b = 0; b < BB; ++b) any |= (dmxb[b] > 0.0f);
        double dice = 2.0 * I / fmax(C, (double)EPS_D);
        out[0] = any ? (float)(1.0 - dice) : 0.0f;
    }
}

extern "C" void kernel_launch(void* const* d_in, const int* in_sizes, int n_in,
                              void* d_out, int out_size, void* d_ws, size_t ws_size,
                              hipStream_t stream) {
    const float* preds = (const float*)d_in[0];
    const float* tg    = (const float*)d_in[1];
    float* out = (float*)d_out;

    float* darr = (float*)d_ws;                  // 8 MB
    u64* dmask  = (u64*)(darr + TOT);            // 256 KB (16B-aligned: 8MB offset)
    float2* part = (float2*)(dmask + BB * 1024); // 16 KB
    float* rowmn = (float*)(part + NBF);         // 32 KB
    float* rowmx = rowmn + BB * HH;              // 32 KB
    float* dmnb  = rowmx + BB * HH;
    float* dmxb  = dmnb + BB;

    hipLaunchKernelGGL(k_maskdil, dim3(BB * 32), dim3(WW), 0, stream, tg, dmask);
    hipLaunchKernelGGL(k_edt, dim3(BB * HH), dim3(WW), 0, stream, dmask, darr, rowmn, rowmx);
    hipLaunchKernelGGL(k_mnmx, dim3(BB), dim3(HH), 0, stream, rowmn, rowmx, dmnb, dmxb);
    hipLaunchKernelGGL(k_final, dim3(NBF), dim3(256), 0, stream,
                       (const float4*)preds, (const float4*)tg, dmask, (const float4*)darr,
                       dmnb, dmxb, part);
    hipLaunchKernelGGL(k_fin, dim3(1), dim3(256), 0, stream, part, dmxb, out);
}

// Round 6
// 103.081 us; speedup vs baseline: 1.6762x; 1.0153x over previous
//
#include <hip/hip_runtime.h>
#include <math.h>

#define BB 32
#define HH 256
#define WW 256
#define HW (HH*WW)
#define TOT (BB*HW)
#define K_BG 0.1f
#define RELAX 5.0f
#define EPS_D 1e-7

typedef unsigned long long u64;
typedef unsigned short u16;

__device__ __forceinline__ float sigf(float x) { return 1.0f / (1.0f + expf(-x)); }

// ---------------- binary 5x5 dilation as bit-ops -> dilated row masks ----------------
// dmask[b*1024 + i*4 + w]: bit j of word w = (dilated target)[b][i][64w+j] != 0
__global__ void k_maskdil(const float* __restrict__ tg, u64* __restrict__ dmask) {
    __shared__ u64 nz[20][4];
    __shared__ u64 hd[20][4];
    int blk = blockIdx.x;              // 32 images x 16 bands of 16 rows
    int b = blk >> 4, band = blk & 15;
    int r0 = band * 16;
    int t = threadIdx.x, w = t >> 6;
    const float* img = tg + b * HW;
    for (int rr = 0; rr < 20; ++rr) {
        int rg = r0 + rr - 2;
        float v = (rg >= 0 && rg < HH) ? img[rg * WW + t] : 0.0f;
        u64 bal = __ballot(v != 0.0f);
        if ((t & 63) == 0) nz[rr][w] = bal;
    }
    __syncthreads();
    if (t < 80) {                      // 20 rows x 4 words: horizontal +-2 dilate
        int rr = t >> 2, k = t & 3;
        u64 m = nz[rr][k];
        u64 ml = (k > 0) ? nz[rr][k - 1] : 0ULL;
        u64 mr = (k < 3) ? nz[rr][k + 1] : 0ULL;
        hd[rr][k] = m | (m << 1) | (m << 2) | (m >> 1) | (m >> 2)
                  | (ml >> 62) | (ml >> 63) | (mr << 62) | (mr << 63);
    }
    __syncthreads();
    if (t < 64) {                      // 16 rows x 4 words: vertical +-2 dilate
        int rr = t >> 2, k = t & 3;
        u64 o = hd[rr][k] | hd[rr + 1][k] | hd[rr + 2][k] | hd[rr + 3][k] | hd[rr + 4][k];
        dmask[b * 1024 + (r0 + rr) * 4 + k] = o;
    }
}

// ---------------- mega: EDT-in-registers + dice partial sums, one block per row ----
// d never hits memory. Vertical distance via bit-scan of the LDS-resident image
// mask (wave-broadcast reads), then the exact early-exit min-plus walk (identical
// f32 arithmetic to the separable reference EDT, incl. the 1e4/1e8 sentinel).
__global__ __launch_bounds__(256) void k_mega(const float* __restrict__ preds,
                                              const float* __restrict__ tg,
                                              const u64* __restrict__ dmask,
                                              float4* __restrict__ part1,
                                              float4* __restrict__ part2) {
    __shared__ u64 mk[1024];           // 8 KB: image's dilated row masks
    __shared__ u16 gS[WW];
    __shared__ float red[8][4];
    int row = blockIdx.x;              // b*256 + i
    int b = row >> 8, i = row & 255;
    int t = threadIdx.x;

    float p  = preds[row * WW + t];    // issued early; consumed after the walk
    float tv = tg[row * WW + t];

    const uint4* src4 = (const uint4*)(dmask + b * 1024);
    uint4* mk4 = (uint4*)mk;
    mk4[t] = src4[t];
    mk4[t + 256] = src4[t + 256];
    __syncthreads();

    int j = t, w = j >> 6;
    u64 bitm = 1ULL << (j & 63);
    int fgbit = (mk[i * 4 + w] & bitm) ? 1 : 0;
    int g0 = 0;
    if (fgbit) {
        int up = 10000;
        for (int k = 1; k <= i; ++k)
            if (!(mk[(i - k) * 4 + w] & bitm)) { up = k; break; }
        int dn = 10000;
        for (int k = 1; k < HH - i; ++k)
            if (!(mk[(i + k) * 4 + w] & bitm)) { dn = k; break; }
        g0 = min(up, dn);
    }
    gS[j] = (u16)g0;
    __syncthreads();

    float gv = (float)g0;
    float best = gv * gv;
    for (int r = 1; r < WW; ++r) {
        float rr = (float)(r * r);
        if (rr >= best) break;
        int jl = j - r, jr = j + r;
        if (jl >= 0) { float v = (float)gS[jl]; best = fminf(best, v * v + rr); }
        if (jr < WW) { float v = (float)gS[jr]; best = fminf(best, v * v + rr); }
    }
    float dv = sqrtf(best);

    float sp = sigf(p);
    float sd = sigf(dv / RELAX);
    float vals[8];
    vals[0] = sp * sd * tv;            // A
    vals[1] = sp * tv;                 // B
    vals[2] = sp * sd;                 // A'
    vals[3] = sp;                      // B'
    vals[4] = sp * (1.0f - (float)fgbit);  // C'
    vals[5] = tv;                      // T
    vals[6] = dv;                      // min
    vals[7] = dv;                      // max
    for (int off = 32; off > 0; off >>= 1) {
        #pragma unroll
        for (int q = 0; q < 6; ++q) vals[q] += __shfl_down(vals[q], off, 64);
        vals[6] = fminf(vals[6], __shfl_down(vals[6], off, 64));
        vals[7] = fmaxf(vals[7], __shfl_down(vals[7], off, 64));
    }
    int wid = t >> 6, lane = t & 63;
    if (lane == 0) {
        #pragma unroll
        for (int q = 0; q < 8; ++q) red[q][wid] = vals[q];
    }
    __syncthreads();
    if (t == 0) {
        float s[8];
        #pragma unroll
        for (int q = 0; q < 6; ++q) s[q] = red[q][0] + red[q][1] + red[q][2] + red[q][3];
        s[6] = fminf(fminf(red[6][0], red[6][1]), fminf(red[6][2], red[6][3]));
        s[7] = fmaxf(fmaxf(red[7][0], red[7][1]), fmaxf(red[7][2], red[7][3]));
        part1[row] = make_float4(s[0], s[1], s[2], s[3]);
        part2[row] = make_float4(s[4], s[5], s[6], s[7]);
    }
}

// ---------------- per-image: fold 256 rows, apply normalization algebra ----------
__global__ void k_img(const float4* __restrict__ part1, const float4* __restrict__ part2,
                      float4* __restrict__ imgout) {
    __shared__ float red[8][4];
    int b = blockIdx.x, t = threadIdx.x;
    float4 p1 = part1[b * HH + t];
    float4 p2 = part2[b * HH + t];
    float vals[8] = {p1.x, p1.y, p1.z, p1.w, p2.x, p2.y, p2.z, p2.w};
    for (int off = 32; off > 0; off >>= 1) {
        #pragma unroll
        for (int q = 0; q < 6; ++q) vals[q] += __shfl_down(vals[q], off, 64);
        vals[6] = fminf(vals[6], __shfl_down(vals[6], off, 64));
        vals[7] = fmaxf(vals[7], __shfl_down(vals[7], off, 64));
    }
    int wid = t >> 6, lane = t & 63;
    if (lane == 0) {
        #pragma unroll
        for (int q = 0; q < 8; ++q) red[q][wid] = vals[q];
    }
    __syncthreads();
    if (t == 0) {
        float A  = red[0][0] + red[0][1] + red[0][2] + red[0][3];
        float Bs = red[1][0] + red[1][1] + red[1][2] + red[1][3];
        float Ap = red[2][0] + red[2][1] + red[2][2] + red[2][3];
        float Bp = red[3][0] + red[3][1] + red[3][2] + red[3][3];
        float Cp = red[4][0] + red[4][1] + red[4][2] + red[4][3];
        float T  = red[5][0] + red[5][1] + red[5][2] + red[5][3];
        float dmn = fminf(fminf(red[6][0], red[6][1]), fminf(red[6][2], red[6][3]));
        float dmx = fmaxf(fmaxf(red[7][0], red[7][1]), fmaxf(red[7][2], red[7][3]));
        float inter, card, any;
        if (dmx > 0.0f) {              // image has foreground
            float smin = sigf(dmn / RELAX);
            float smax = sigf(dmx / RELAX);
            float m = smax - smin;
            float denom = (m > 0.0f) ? m : 1.0f;
            inter = (A - smin * Bs) / denom;            // Σ sp·t·(1-fat) == 0 exactly
            card  = (Ap - smin * Bp) / denom + K_BG * Cp + T;
            any = 1.0f;
        } else {                       // dm = 1 - t ; t == 0 everywhere
            inter = 0.0f;
            card = Bp - Bs + T;
            any = 0.0f;
        }
        imgout[b] = make_float4(inter, card, any, 0.0f);
    }
}

// ---------------- finalize scalar ----------------
__global__ void k_fin(const float4* __restrict__ imgout, float* __restrict__ out) {
    if (threadIdx.x == 0) {
        double I = 0.0, C = 0.0;
        int any = 0;
        for (int b = 0; b < BB; ++b) {
            float4 v = imgout[b];
            I += (double)v.x; C += (double)v.y;
            any |= (v.z > 0.0f);
        }
        double dice = 2.0 * I / fmax(C, (double)EPS_D);
        out[0] = any ? (float)(1.0 - dice) : 0.0f;
    }
}

extern "C" void kernel_launch(void* const* d_in, const int* in_sizes, int n_in,
                              void* d_out, int out_size, void* d_ws, size_t ws_size,
                              hipStream_t stream) {
    const float* preds = (const float*)d_in[0];
    const float* tg    = (const float*)d_in[1];
    float* out = (float*)d_out;

    u64* dmask   = (u64*)d_ws;                    // 256 KB
    float4* part1 = (float4*)(dmask + BB * 1024); // 128 KB, 16B-aligned
    float4* part2 = part1 + BB * HH;              // 128 KB
    float4* imgout = part2 + BB * HH;             // 512 B

    hipLaunchKernelGGL(k_maskdil, dim3(BB * 16), dim3(WW), 0, stream, tg, dmask);
    hipLaunchKernelGGL(k_mega, dim3(BB * HH), dim3(WW), 0, stream, preds, tg, dmask,
                       part1, part2);
    hipLaunchKernelGGL(k_img, dim3(BB), dim3(HH), 0, stream, part1, part2, imgout);
    hipLaunchKernelGGL(k_fin, dim3(1), dim3(64), 0, stream, imgout, out);
}